// Round 1
// baseline (2591.882 us; speedup 1.0000x reference)
//
#include <hip/hip_runtime.h>

// ---------------------------------------------------------------------------
// PointNet++-style segmentation module on MI355X.
// Pipeline: FPS -> ball query -> gather+concat -> 3x (MFMA GEMM + BN + ReLU)
//           -> maxpool(s) -> conv1(+BN,ReLU) -> conv2(+BN,ReLU) -> conv3(+bias)
// FPS / ball-query comparisons are computed with exact f32 ops (no FMA
// contraction) so selected indices match the numpy reference bit-for-bit.
// ---------------------------------------------------------------------------

typedef __attribute__((ext_vector_type(8))) short short8v;
typedef __attribute__((ext_vector_type(4))) short short4v;
typedef __attribute__((ext_vector_type(4))) float f32x4;

#define DEVFN static __device__ __forceinline__

DEVFN unsigned short f2bf(float f) {  // round-to-nearest-even f32 -> bf16
  union { float f; unsigned u; } v; v.f = f;
  unsigned r = v.u + 0x7fffu + ((v.u >> 16) & 1u);
  return (unsigned short)(r >> 16);
}
DEVFN float bf2f(unsigned short h) {
  union { unsigned u; float f; } v; v.u = ((unsigned)h) << 16;
  return v.f;
}

// ---------------------------------------------------------------------------
// FPS: one block per batch, 1024 threads, 16 points/thread in registers.
// Exact f32 distance math (matches numpy op order: ((dx^2+dy^2)+dz^2)).
// ---------------------------------------------------------------------------
__global__ __launch_bounds__(1024) void fps_kernel(const float* __restrict__ xyz,
                                                   int* __restrict__ fps_inds,
                                                   float* __restrict__ new_xyz) {
  const int b = blockIdx.x;
  const int t = threadIdx.x;
  const float* base = xyz + (size_t)b * 16384 * 3;
  float px[16], py[16], pz[16], d[16];
#pragma unroll
  for (int i = 0; i < 16; ++i) {
    int p = i * 1024 + t;
    px[i] = base[p * 3 + 0];
    py[i] = base[p * 3 + 1];
    pz[i] = base[p * 3 + 2];
    d[i] = 1e10f;
  }
  __shared__ float sv[16];
  __shared__ int si[16];
  __shared__ float s_lx, s_ly, s_lz;
  if (t == 0) {
    s_lx = px[0]; s_ly = py[0]; s_lz = pz[0];
    fps_inds[b * 1024] = 0;
    new_xyz[(size_t)b * 3072 + 0] = px[0];
    new_xyz[(size_t)b * 3072 + 1] = py[0];
    new_xyz[(size_t)b * 3072 + 2] = pz[0];
  }
  __syncthreads();
  float lx = s_lx, ly = s_ly, lz = s_lz;
  const int wid = t >> 6, lane = t & 63;
  for (int k = 1; k < 1024; ++k) {
    bool changed = false;
#pragma unroll
    for (int i = 0; i < 16; ++i) {
      float dx = __fsub_rn(px[i], lx);
      float dy = __fsub_rn(py[i], ly);
      float dz = __fsub_rn(pz[i], lz);
      float d2 = __fadd_rn(__fadd_rn(__fmul_rn(dx, dx), __fmul_rn(dy, dy)), __fmul_rn(dz, dz));
      if (d2 < d[i]) { d[i] = d2; changed = true; }
    }
    // If no lane in this wave lowered a dist, this wave's LDS slot (its
    // current max) is still exact -> skip rescan + wave reduce.
    if (__any((int)changed)) {
      float bv = -1.0f; int bi = 0x7fffffff;
#pragma unroll
      for (int i = 0; i < 16; ++i) {
        if (d[i] > bv) { bv = d[i]; bi = i * 1024 + t; }  // strict > keeps lowest idx
      }
#pragma unroll
      for (int m = 1; m < 64; m <<= 1) {
        float ov = __shfl_xor(bv, m);
        int oi = __shfl_xor(bi, m);
        if (ov > bv || (ov == bv && oi < bi)) { bv = ov; bi = oi; }
      }
      if (lane == 0) { sv[wid] = bv; si[wid] = bi; }
    }
    __syncthreads();
    // every wave reduces the 16 wave-winners (replicated butterfly)
    float vw = sv[lane & 15];
    int iw = si[lane & 15];
#pragma unroll
    for (int m = 1; m < 16; m <<= 1) {
      float ov = __shfl_xor(vw, m);
      int oi = __shfl_xor(iw, m);
      if (ov > vw || (ov == vw && oi < iw)) { vw = ov; iw = oi; }
    }
    if (t == 0) fps_inds[b * 1024 + k] = iw;
    if (t == (iw & 1023)) {  // owner publishes winner coords
      int ii = iw >> 10;
      float sx = px[0], sy = py[0], sz = pz[0];
#pragma unroll
      for (int j = 1; j < 16; ++j) {
        if (ii == j) { sx = px[j]; sy = py[j]; sz = pz[j]; }
      }
      s_lx = sx; s_ly = sy; s_lz = sz;
      new_xyz[((size_t)b * 1024 + k) * 3 + 0] = sx;
      new_xyz[((size_t)b * 1024 + k) * 3 + 1] = sy;
      new_xyz[((size_t)b * 1024 + k) * 3 + 2] = sz;
    }
    __syncthreads();
    lx = s_lx; ly = s_ly; lz = s_lz;
  }
}

// ---------------------------------------------------------------------------
// Ball query: one wave per center; collect first 16 in-radius indices in
// ascending index order; pad with the first. Also emits normalized grouped
// xyz (bf16, 4 elems/slot) for GEMM0's xyz channels.
// ---------------------------------------------------------------------------
__global__ __launch_bounds__(256) void ballquery_kernel(const float* __restrict__ xyz,
                                                        const float* __restrict__ new_xyz,
                                                        int* __restrict__ idxbuf,
                                                        unsigned short* __restrict__ gxyz) {
  const int wid = threadIdx.x >> 6, lane = threadIdx.x & 63;
  const int center = blockIdx.x * 4 + wid;  // 0..8191
  const int b = center >> 10;
  const float* base = xyz + (size_t)b * 49152;
  const float cx = new_xyz[(size_t)center * 3 + 0];
  const float cy = new_xyz[(size_t)center * 3 + 1];
  const float cz = new_xyz[(size_t)center * 3 + 2];
  __shared__ int slots[4][16];
  int count = 0;
  for (int c = 0; c < 256; ++c) {
    int p = c * 64 + lane;
    float dx = __fsub_rn(cx, base[p * 3 + 0]);
    float dy = __fsub_rn(cy, base[p * 3 + 1]);
    float dz = __fsub_rn(cz, base[p * 3 + 2]);
    float d2 = __fadd_rn(__fadd_rn(__fmul_rn(dx, dx), __fmul_rn(dy, dy)), __fmul_rn(dz, dz));
    bool inr = d2 < 0.09f;
    unsigned long long mask = __ballot((int)inr);
    int rank = __popcll(mask & ((1ull << lane) - 1ull));
    int pos = count + rank;
    if (inr && pos < 16) slots[wid][pos] = p;
    count += __popcll(mask);
    if (count >= 16) break;  // wave-uniform
  }
  __asm__ volatile("s_waitcnt lgkmcnt(0)" ::: "memory");
  if (lane < 16) {
    int eff = count < 16 ? count : 16;
    int p = slots[wid][lane < eff ? lane : 0];
    idxbuf[(size_t)center * 16 + lane] = p;
    float gx = (base[p * 3 + 0] - cx) * (1.0f / 0.3f);
    float gy = (base[p * 3 + 1] - cy) * (1.0f / 0.3f);
    float gz = (base[p * 3 + 2] - cz) * (1.0f / 0.3f);
    short4v o;
    o[0] = (short)f2bf(gx); o[1] = (short)f2bf(gy); o[2] = (short)f2bf(gz); o[3] = 0;
    *(short4v*)(gxyz + (size_t)center * 64 + lane * 4) = o;
  }
}

// ---------------------------------------------------------------------------
// Transpose features (B,256,16384) f32 -> featT (B*16384, 256) bf16
// ---------------------------------------------------------------------------
__global__ __launch_bounds__(256) void transpose_kernel(const float* __restrict__ feat,
                                                        unsigned short* __restrict__ featT) {
  __shared__ float tile[32][33];
  int blk = blockIdx.x;
  int pt = blk & 511;
  int ct = (blk >> 9) & 7;
  int b = blk >> 12;
  int tx = threadIdx.x & 31, ty = threadIdx.x >> 5;
  const float* src = feat + ((size_t)b * 256 + ct * 32) * 16384 + pt * 32;
#pragma unroll
  for (int q = 0; q < 4; ++q) {
    int ch = ty + q * 8;
    tile[ch][tx] = src[(size_t)ch * 16384 + tx];
  }
  __syncthreads();
  unsigned short* dst = featT + ((size_t)b * 16384 + (size_t)pt * 32) * 256 + ct * 32;
#pragma unroll
  for (int q = 0; q < 4; ++q) {
    int r = ty + q * 8;
    dst[(size_t)r * 256 + tx] = f2bf(tile[tx][r]);
  }
}

// ---------------------------------------------------------------------------
// GEMM: out(128 x ncols) = W(128 x K) * X(K x ncols), MFMA 16x16x32 bf16.
// Block: 256 threads (4 waves, 2x2), tile 128 rows x 64 cols.
// MODE 0: B gathered from featT via idxbuf + gxyz (K=288), stats, Yout bf16
// MODE 1: B from Yin with BN+ReLU applied (K=128), stats, Yout bf16
// MODE 2: B from Yin plain (K=128), stats, Yout bf16
// MODE 3: B from Yin with BN+ReLU (K=128), no stats, f32 out + bias (64 ch)
// ---------------------------------------------------------------------------
template <int MODE>
__global__ __launch_bounds__(256) void gemm_kernel(
    const unsigned short* __restrict__ W,
    const unsigned short* __restrict__ Bsrc,
    const int* __restrict__ idxbuf,
    const unsigned short* __restrict__ gxyz,
    const float* __restrict__ bnp,
    unsigned short* __restrict__ Yout,
    float* __restrict__ outf,
    const float* __restrict__ bias,
    float* __restrict__ partials) {
  constexpr bool GATHER = (MODE == 0);
  constexpr bool BNIN = (MODE == 1 || MODE == 3);
  constexpr bool STATS = (MODE <= 2);
  constexpr bool OUTF32 = (MODE == 3);
  constexpr int KCH = GATHER ? 9 : 4;
  constexpr int K = GATHER ? 288 : 128;
  __shared__ unsigned short lA[128 * 40];  // +16B padded stride vs bank conflicts
  __shared__ unsigned short lB[64 * 40];
  const int tid = threadIdx.x;
  const int wid = tid >> 6, lane = tid & 63;
  const int wr = wid >> 1, wc = wid & 1;
  const int lm = lane & 15, lg = lane >> 4;
  const int c0 = blockIdx.x * 64;
  const int colL = tid >> 2, part = tid & 3;
  const int col = c0 + colL;
  int gat_p = 0, gat_b = 0;
  if constexpr (GATHER) { gat_b = col >> 14; gat_p = idxbuf[col]; }
  f32x4 acc[4][2] = {};
  for (int q = 0; q < KCH; ++q) {
    __syncthreads();
    // stage A (weights) : 128 rows x 32 k
#pragma unroll
    for (int pass = 0; pass < 2; ++pass) {
      int u = pass * 256 + tid;
      int r = u >> 2, qq = u & 3;
      short8v w = *(const short8v*)(W + (size_t)r * K + q * 32 + qq * 8);
      *(short8v*)(&lA[r * 40 + qq * 8]) = w;
    }
    // stage B : 64 cols x 32 k
    short8v bv = short8v{0, 0, 0, 0, 0, 0, 0, 0};
    if constexpr (GATHER) {
      if (q < 8) {
        bv = *(const short8v*)(Bsrc + ((size_t)(gat_b << 14) + gat_p) * 256 + q * 32 + part * 8);
      } else if (part == 0) {
        short4v g = *(const short4v*)(gxyz + (size_t)col * 4);
        bv[0] = g[0]; bv[1] = g[1]; bv[2] = g[2];
      }
    } else {
      short8v raw = *(const short8v*)(Bsrc + (size_t)col * 128 + q * 32 + part * 8);
      if constexpr (BNIN) {
        int k0 = q * 32 + part * 8;
#pragma unroll
        for (int e = 0; e < 8; ++e) {
          float v = bf2f((unsigned short)raw[e]) * bnp[k0 + e] + bnp[128 + k0 + e];
          v = fmaxf(v, 0.0f);
          raw[e] = (short)f2bf(v);
        }
      }
      bv = raw;
    }
    *(short8v*)(&lB[colL * 40 + part * 8]) = bv;
    __syncthreads();
    // compute
    short8v b0 = *(const short8v*)(&lB[(wc * 32 + 0 + lm) * 40 + lg * 8]);
    short8v b1 = *(const short8v*)(&lB[(wc * 32 + 16 + lm) * 40 + lg * 8]);
#pragma unroll
    for (int mb = 0; mb < 4; ++mb) {
      short8v a = *(const short8v*)(&lA[(wr * 64 + mb * 16 + lm) * 40 + lg * 8]);
      acc[mb][0] = __builtin_amdgcn_mfma_f32_16x16x32_bf16(a, b0, acc[mb][0], 0, 0, 0);
      acc[mb][1] = __builtin_amdgcn_mfma_f32_16x16x32_bf16(a, b1, acc[mb][1], 0, 0, 0);
    }
  }
  // ---- epilogue ----
  if constexpr (STATS) {  // per-channel sum / sumsq partials for batch-norm
    const int slotstride = gridDim.x * 2;
    const int slot = blockIdx.x * 2 + wc;
#pragma unroll
    for (int mb = 0; mb < 4; ++mb) {
#pragma unroll
      for (int j = 0; j < 4; ++j) {
        float a0 = acc[mb][0][j], a1 = acc[mb][1][j];
        float s = a0 + a1;
        float qs = a0 * a0 + a1 * a1;
#pragma unroll
        for (int m = 1; m < 16; m <<= 1) { s += __shfl_xor(s, m); qs += __shfl_xor(qs, m); }
        if (lm == 0) {
          int ch = wr * 64 + mb * 16 + lg * 4 + j;
          partials[(size_t)(ch * 2) * slotstride + slot] = s;
          partials[(size_t)(ch * 2 + 1) * slotstride + slot] = qs;
        }
      }
    }
  }
  if constexpr (!OUTF32) {
#pragma unroll
    for (int mb = 0; mb < 4; ++mb)
#pragma unroll
      for (int nb = 0; nb < 2; ++nb) {
        int colg = c0 + wc * 32 + nb * 16 + lm;
        int ch = wr * 64 + mb * 16 + lg * 4;
#pragma unroll
        for (int j = 0; j < 4; ++j)
          Yout[(size_t)colg * 128 + ch + j] = f2bf(acc[mb][nb][j]);
      }
  } else {
    if (wr == 0) {  // only ch 0..63 are real (W padded with zero rows)
#pragma unroll
      for (int mb = 0; mb < 4; ++mb)
#pragma unroll
        for (int nb = 0; nb < 2; ++nb) {
          int colg = c0 + wc * 32 + nb * 16 + lm;
          int bb = colg >> 10, n = colg & 1023;
#pragma unroll
          for (int j = 0; j < 4; ++j) {
            int ch = mb * 16 + lg * 4 + j;
            outf[((size_t)bb * 64 + ch) * 1024 + n] = acc[mb][nb][j] + bias[ch];
          }
        }
    }
  }
}

// ---------------------------------------------------------------------------
// BN finalize: one block per channel; reduce partials -> scale/shift
// ---------------------------------------------------------------------------
__global__ __launch_bounds__(256) void bn_finalize(const float* __restrict__ part, int nslot,
                                                   float inv, const float* __restrict__ g,
                                                   const float* __restrict__ b,
                                                   float* __restrict__ bnp) {
  int ch = blockIdx.x;
  int t = threadIdx.x;
  float s1 = 0.f, s2 = 0.f;
  for (int i = t; i < nslot; i += 256) {
    s1 += part[(size_t)(ch * 2) * nslot + i];
    s2 += part[(size_t)(ch * 2 + 1) * nslot + i];
  }
  __shared__ float r1[256], r2[256];
  r1[t] = s1; r2[t] = s2;
  __syncthreads();
  for (int s = 128; s > 0; s >>= 1) {
    if (t < s) { r1[t] += r1[t + s]; r2[t] += r2[t + s]; }
    __syncthreads();
  }
  if (t == 0) {
    float m = r1[0] * inv;
    float var = r2[0] * inv - m * m;
    float sc = g[ch] * rsqrtf(var + 1e-5f);
    bnp[ch] = sc;
    bnp[128 + ch] = b[ch] - m * sc;
  }
}

// ---------------------------------------------------------------------------
// Maxpool over the 16 samples + apply BN2 + ReLU -> feat (b*n, 128) bf16
// Tracks max AND min so the BN-affine/max swap is exact for any scale sign.
// ---------------------------------------------------------------------------
__global__ __launch_bounds__(256) void maxpool_kernel(const unsigned short* __restrict__ Y2,
                                                      const float* __restrict__ bnp,
                                                      unsigned short* __restrict__ feat) {
  int gidx = blockIdx.x * 256 + threadIdx.x;  // 131072
  int ng = gidx >> 4, cg = gidx & 15;
  int ch0 = cg * 8;
  float mx[8], mn[8];
#pragma unroll
  for (int e = 0; e < 8; ++e) { mx[e] = -3.4e38f; mn[e] = 3.4e38f; }
  for (int s = 0; s < 16; ++s) {
    short8v v = *(const short8v*)(Y2 + ((size_t)ng * 16 + s) * 128 + ch0);
#pragma unroll
    for (int e = 0; e < 8; ++e) {
      float f = bf2f((unsigned short)v[e]);
      mx[e] = fmaxf(mx[e], f);
      mn[e] = fminf(mn[e], f);
    }
  }
  short8v o;
#pragma unroll
  for (int e = 0; e < 8; ++e) {
    float sc = bnp[ch0 + e], sh = bnp[128 + ch0 + e];
    float v = (sc >= 0.f ? mx[e] : mn[e]) * sc + sh;
    v = fmaxf(v, 0.0f);
    o[e] = (short)f2bf(v);
  }
  *(short8v*)(feat + (size_t)ng * 128 + ch0) = o;
}

// ---------------------------------------------------------------------------
// Weight prep: f32 -> bf16, permute W0 (features first, xyz at k=256..258),
// pad W0 K to 288, pad conv3 to 128 output rows.
// ---------------------------------------------------------------------------
__global__ __launch_bounds__(256) void prep_weights(const float* __restrict__ w0,
                                                    const float* __restrict__ w1,
                                                    const float* __restrict__ w2,
                                                    const float* __restrict__ c1,
                                                    const float* __restrict__ c2,
                                                    const float* __restrict__ c3,
                                                    unsigned short* __restrict__ W0p,
                                                    unsigned short* __restrict__ W1p,
                                                    unsigned short* __restrict__ W2p,
                                                    unsigned short* __restrict__ C1p,
                                                    unsigned short* __restrict__ C2p,
                                                    unsigned short* __restrict__ C3p) {
  int i = blockIdx.x * 256 + threadIdx.x;
  if (i < 36864) {
    int r = i / 288, c = i % 288;
    float v = 0.0f;
    if (c < 256) v = w0[r * 259 + 3 + c];
    else if (c < 259) v = w0[r * 259 + (c - 256)];
    W0p[i] = f2bf(v);
  }
  int j = i - 36864;
  if (j >= 0 && j < 16384) W1p[j] = f2bf(w1[j]);
  j -= 16384;
  if (j >= 0 && j < 16384) W2p[j] = f2bf(w2[j]);
  j -= 16384;
  if (j >= 0 && j < 16384) C1p[j] = f2bf(c1[j]);
  j -= 16384;
  if (j >= 0 && j < 16384) C2p[j] = f2bf(c2[j]);
  j -= 16384;
  if (j >= 0 && j < 16384) C3p[j] = (j < 8192) ? f2bf(c3[j]) : (unsigned short)0;
}

// ---------------------------------------------------------------------------
extern "C" void kernel_launch(void* const* d_in, const int* in_sizes, int n_in,
                              void* d_out, int out_size, void* d_ws, size_t ws_size,
                              hipStream_t stream) {
  const float* xyz = (const float*)d_in[0];
  const float* features = (const float*)d_in[1];
  const float* mlp_w0 = (const float*)d_in[2];
  const float* mlp_g0 = (const float*)d_in[3];
  const float* mlp_b0 = (const float*)d_in[4];
  const float* mlp_w1 = (const float*)d_in[5];
  const float* mlp_g1 = (const float*)d_in[6];
  const float* mlp_b1 = (const float*)d_in[7];
  const float* mlp_w2 = (const float*)d_in[8];
  const float* mlp_g2 = (const float*)d_in[9];
  const float* mlp_b2 = (const float*)d_in[10];
  const float* conv1_w = (const float*)d_in[11];
  const float* bn1_g = (const float*)d_in[13];
  const float* bn1_b = (const float*)d_in[14];
  const float* conv2_w = (const float*)d_in[15];
  const float* bn2_g = (const float*)d_in[17];
  const float* bn2_b = (const float*)d_in[18];
  const float* conv3_w = (const float*)d_in[19];
  const float* conv3_b = (const float*)d_in[20];

  char* ws = (char*)d_ws;
  int* fps_inds = (int*)(ws + 0);                    //   32768
  float* new_xyz = (float*)(ws + 32768);             //   98304
  int* idxbuf = (int*)(ws + 131072);                 //  524288
  unsigned short* gxyz = (unsigned short*)(ws + 655360);   // 1048576
  float* bnp0 = (float*)(ws + 1703936);
  float* bnp1 = (float*)(ws + 1704960);
  float* bnp2 = (float*)(ws + 1705984);
  float* bnpc1 = (float*)(ws + 1707008);
  float* bnpc2 = (float*)(ws + 1708032);
  unsigned short* W0p = (unsigned short*)(ws + 1709056);   // 73728
  unsigned short* W1p = (unsigned short*)(ws + 1782784);
  unsigned short* W2p = (unsigned short*)(ws + 1815552);
  unsigned short* C1p = (unsigned short*)(ws + 1848320);
  unsigned short* C2p = (unsigned short*)(ws + 1881088);
  unsigned short* C3p = (unsigned short*)(ws + 1913856);
  unsigned short* feat = (unsigned short*)(ws + 1946624);  // 2 MB
  unsigned short* G1 = (unsigned short*)(ws + 4043776);    // 2 MB
  unsigned short* G2 = (unsigned short*)(ws + 6140928);    // 2 MB
  float* partials = (float*)(ws + 8388608);                // 4 MB
  unsigned short* featT = (unsigned short*)(ws + 16777216);  // 64 MB
  unsigned short* Y0 = (unsigned short*)(ws + 83886080);     // 32 MB
  unsigned short* Y1 = featT;  // featT dead after GEMM0
  unsigned short* Y2 = Y0;     // Y0 dead after GEMM1
  float* outp = (float*)d_out;

  prep_weights<<<464, 256, 0, stream>>>(mlp_w0, mlp_w1, mlp_w2, conv1_w, conv2_w, conv3_w,
                                        W0p, W1p, W2p, C1p, C2p, C3p);
  fps_kernel<<<8, 1024, 0, stream>>>(xyz, fps_inds, new_xyz);
  transpose_kernel<<<32768, 256, 0, stream>>>(features, featT);
  ballquery_kernel<<<2048, 256, 0, stream>>>(xyz, new_xyz, idxbuf, gxyz);

  // MLP layer 0 (K=288, gather), then BN stats
  gemm_kernel<0><<<2048, 256, 0, stream>>>(W0p, featT, idxbuf, gxyz, nullptr, Y0, nullptr,
                                           nullptr, partials);
  bn_finalize<<<128, 256, 0, stream>>>(partials, 4096, 1.0f / 131072.0f, mlp_g0, mlp_b0, bnp0);
  // MLP layer 1
  gemm_kernel<1><<<2048, 256, 0, stream>>>(W1p, Y0, nullptr, nullptr, bnp0, Y1, nullptr,
                                           nullptr, partials);
  bn_finalize<<<128, 256, 0, stream>>>(partials, 4096, 1.0f / 131072.0f, mlp_g1, mlp_b1, bnp1);
  // MLP layer 2
  gemm_kernel<1><<<2048, 256, 0, stream>>>(W2p, Y1, nullptr, nullptr, bnp1, Y2, nullptr,
                                           nullptr, partials);
  bn_finalize<<<128, 256, 0, stream>>>(partials, 4096, 1.0f / 131072.0f, mlp_g2, mlp_b2, bnp2);
  // maxpool + BN2 + ReLU
  maxpool_kernel<<<512, 256, 0, stream>>>(Y2, bnp2, feat);
  // conv1 (bias cancels under BN), stats
  gemm_kernel<2><<<128, 256, 0, stream>>>(C1p, feat, nullptr, nullptr, nullptr, G1, nullptr,
                                          nullptr, partials);
  bn_finalize<<<128, 256, 0, stream>>>(partials, 256, 1.0f / 8192.0f, bn1_g, bn1_b, bnpc1);
  // conv2 (applies BN1+ReLU on input; bias cancels under BN), stats
  gemm_kernel<1><<<128, 256, 0, stream>>>(C2p, G1, nullptr, nullptr, bnpc1, G2, nullptr,
                                          nullptr, partials);
  bn_finalize<<<128, 256, 0, stream>>>(partials, 256, 1.0f / 8192.0f, bn2_g, bn2_b, bnpc2);
  // conv3 (applies BN2+ReLU on input; +bias; f32 out)
  gemm_kernel<3><<<128, 256, 0, stream>>>(C3p, G2, nullptr, nullptr, bnpc2, nullptr, outp,
                                          conv3_b, partials);
  (void)in_sizes; (void)n_in; (void)out_size; (void)ws_size;
}

// Round 2
// 2549.637 us; speedup vs baseline: 1.0166x; 1.0166x over previous
//
#include <hip/hip_runtime.h>

// ---------------------------------------------------------------------------
// PointNet++-style segmentation module on MI355X.
// Pipeline: FPS (exact, bbox-pruned) -> ball query -> gather+concat ->
//           3x (MFMA GEMM + BN + ReLU) -> maxpool -> conv1/2 (+BN,ReLU) ->
//           conv3 (+bias).
// FPS / ball-query comparisons use exact f32 ops (no FMA contraction) so
// selected indices match the numpy reference bit-for-bit. FPS pruning is
// conservative (margin 1e-5 >> 7 ulp of rounding) -> lossless skips.
// ---------------------------------------------------------------------------

typedef __attribute__((ext_vector_type(8))) short short8v;
typedef __attribute__((ext_vector_type(4))) short short4v;
typedef __attribute__((ext_vector_type(4))) float f32x4;

#define DEVFN static __device__ __forceinline__

DEVFN unsigned short f2bf(float f) {  // round-to-nearest-even f32 -> bf16
  union { float f; unsigned u; } v; v.f = f;
  unsigned r = v.u + 0x7fffu + ((v.u >> 16) & 1u);
  return (unsigned short)(r >> 16);
}
DEVFN float bf2f(unsigned short h) {
  union { unsigned u; float f; } v; v.u = ((unsigned)h) << 16;
  return v.f;
}
DEVFN unsigned fenc(float f) {  // monotone float->uint map (no NaN inputs)
  unsigned u = __float_as_uint(f);
  return (u & 0x80000000u) ? ~u : (u | 0x80000000u);
}
DEVFN float fdec(unsigned e) {
  unsigned u = (e & 0x80000000u) ? (e & 0x7fffffffu) : ~e;
  return __uint_as_float(u);
}
DEVFN int spread4(int v) {  // bits 0..3 -> 0,3,6,9
  return (v & 1) | ((v & 2) << 2) | ((v & 4) << 4) | ((v & 8) << 6);
}

// ---------------------------------------------------------------------------
// FPS: one block per batch, 1024 threads. Phase 1: Morton counting sort so
// each thread owns 16 spatially-local points. Phase 2: 1023 serial argmax
// iterations with exact bbox pruning, cached winners, 1 barrier/iter.
// ---------------------------------------------------------------------------
__global__ __launch_bounds__(1024) void fps_kernel(const float* __restrict__ xyz,
                                                   int* __restrict__ fps_inds,
                                                   float* __restrict__ new_xyz,
                                                   float* __restrict__ sortbuf) {
  const int b = blockIdx.x;
  const int t = threadIdx.x;
  const int wid = t >> 6, lane = t & 63;
  const float* base = xyz + (size_t)b * 49152;
  float* sX = sortbuf + (size_t)b * 65536;
  float* sY = sX + 16384;
  float* sZ = sX + 32768;
  int* sI = (int*)(sX + 49152);

  __shared__ int shist[4096];
  __shared__ unsigned sbb[6];  // encoded batch bbox: min xyz, max xyz
  __shared__ int wtot[16];
  __shared__ float sv[16][2];
  __shared__ int si[16][2];

  // ---- Phase A: load raw points (strided), reduce batch bbox ----
  float px[16], py[16], pz[16];
#pragma unroll
  for (int i = 0; i < 16; ++i) {
    int p = i * 1024 + t;
    px[i] = base[p * 3 + 0];
    py[i] = base[p * 3 + 1];
    pz[i] = base[p * 3 + 2];
  }
  if (t < 3) sbb[t] = 0xFFFFFFFFu;
  else if (t < 6) sbb[t] = 0u;
  float mnx = px[0], mny = py[0], mnz = pz[0], mxx = px[0], mxy = py[0], mxz = pz[0];
#pragma unroll
  for (int i = 1; i < 16; ++i) {
    mnx = fminf(mnx, px[i]); mny = fminf(mny, py[i]); mnz = fminf(mnz, pz[i]);
    mxx = fmaxf(mxx, px[i]); mxy = fmaxf(mxy, py[i]); mxz = fmaxf(mxz, pz[i]);
  }
#pragma unroll
  for (int m = 1; m < 64; m <<= 1) {
    mnx = fminf(mnx, __shfl_xor(mnx, m)); mny = fminf(mny, __shfl_xor(mny, m));
    mnz = fminf(mnz, __shfl_xor(mnz, m)); mxx = fmaxf(mxx, __shfl_xor(mxx, m));
    mxy = fmaxf(mxy, __shfl_xor(mxy, m)); mxz = fmaxf(mxz, __shfl_xor(mxz, m));
  }
  __syncthreads();
  if (lane == 0) {
    atomicMin(&sbb[0], fenc(mnx)); atomicMin(&sbb[1], fenc(mny)); atomicMin(&sbb[2], fenc(mnz));
    atomicMax(&sbb[3], fenc(mxx)); atomicMax(&sbb[4], fenc(mxy)); atomicMax(&sbb[5], fenc(mxz));
  }
  for (int j = t; j < 4096; j += 1024) shist[j] = 0;
  __syncthreads();
  const float bbminx = fdec(sbb[0]), bbminy = fdec(sbb[1]), bbminz = fdec(sbb[2]);
  const float sclx = 16.0f / fmaxf(fdec(sbb[3]) - bbminx, 1e-20f);
  const float scly = 16.0f / fmaxf(fdec(sbb[4]) - bbminy, 1e-20f);
  const float sclz = 16.0f / fmaxf(fdec(sbb[5]) - bbminz, 1e-20f);

  // ---- Phase B: histogram of morton codes ----
  int code[16];
#pragma unroll
  for (int i = 0; i < 16; ++i) {
    int cx = min(15, (int)((px[i] - bbminx) * sclx));
    int cy = min(15, (int)((py[i] - bbminy) * scly));
    int cz = min(15, (int)((pz[i] - bbminz) * sclz));
    code[i] = spread4(cx) | (spread4(cy) << 1) | (spread4(cz) << 2);
    atomicAdd(&shist[code[i]], 1);
  }
  __syncthreads();

  // ---- Phase C: exclusive scan of 4096 bins ----
  int c0 = t * 4;
  int h0 = shist[c0], h1 = shist[c0 + 1], h2 = shist[c0 + 2], h3 = shist[c0 + 3];
  int s4 = h0 + h1 + h2 + h3;
  int sc = s4;
#pragma unroll
  for (int off = 1; off < 64; off <<= 1) {
    int v = __shfl_up(sc, off);
    if (lane >= off) sc += v;
  }
  if (lane == 63) wtot[wid] = sc;
  __syncthreads();
  int wbase = 0;
  for (int w = 0; w < 16; ++w) {
    int wv_ = wtot[w];
    if (w < wid) wbase += wv_;
  }
  int excl = wbase + sc - s4;
  shist[c0] = excl;
  shist[c0 + 1] = excl + h0;
  shist[c0 + 2] = excl + h0 + h1;
  shist[c0 + 3] = excl + h0 + h1 + h2;
  __syncthreads();

  // ---- Phase D: scatter to sorted order (intra-cell order arbitrary;
  //      correctness preserved by orig-index tie-breaks everywhere) ----
#pragma unroll
  for (int i = 0; i < 16; ++i) {
    int pos = atomicAdd(&shist[code[i]], 1);
    sX[pos] = px[i]; sY[pos] = py[i]; sZ[pos] = pz[i];
    sI[pos] = i * 1024 + t;
  }
  __syncthreads();

  // ---- Phase E: reload sorted run of 16, thread & wave bboxes ----
  int ix[16];
#pragma unroll
  for (int q = 0; q < 4; ++q) {
    f32x4 vx = ((const f32x4*)(sX + t * 16))[q];
    f32x4 vy = ((const f32x4*)(sY + t * 16))[q];
    f32x4 vz = ((const f32x4*)(sZ + t * 16))[q];
#pragma unroll
    for (int e = 0; e < 4; ++e) { px[q * 4 + e] = vx[e]; py[q * 4 + e] = vy[e]; pz[q * 4 + e] = vz[e]; }
    *(int4*)(&ix[q * 4]) = ((const int4*)(sI + t * 16))[q];
  }
  float bnx = px[0], bny = py[0], bnz = pz[0], bxx = px[0], bxy = py[0], bxz = pz[0];
  float d[16];
#pragma unroll
  for (int i = 0; i < 16; ++i) {
    bnx = fminf(bnx, px[i]); bny = fminf(bny, py[i]); bnz = fminf(bnz, pz[i]);
    bxx = fmaxf(bxx, px[i]); bxy = fmaxf(bxy, py[i]); bxz = fmaxf(bxz, pz[i]);
    d[i] = 1e10f;
  }
  float wbnx = bnx, wbny = bny, wbnz = bnz, wbxx = bxx, wbxy = bxy, wbxz = bxz;
#pragma unroll
  for (int m = 1; m < 64; m <<= 1) {
    wbnx = fminf(wbnx, __shfl_xor(wbnx, m)); wbny = fminf(wbny, __shfl_xor(wbny, m));
    wbnz = fminf(wbnz, __shfl_xor(wbnz, m)); wbxx = fmaxf(wbxx, __shfl_xor(wbxx, m));
    wbxy = fmaxf(wbxy, __shfl_xor(wbxy, m)); wbxz = fmaxf(wbxz, __shfl_xor(wbxz, m));
  }

  float my_max = 1e10f;
  int my_arg = 0x7fffffff;
  float wv = 1e10f;
  int wi = 0x7fffffff;

  float lx = base[0], ly = base[1], lz = base[2];
  if (t == 0) {
    fps_inds[b * 1024] = 0;
    new_xyz[(size_t)b * 3072 + 0] = lx;
    new_xyz[(size_t)b * 3072 + 1] = ly;
    new_xyz[(size_t)b * 3072 + 2] = lz;
  }

  // ---- Phase F: 1023 serial selections ----
  for (int k = 1; k < 1024; ++k) {
    const int par = k & 1;
    // wave-level prune (conservative: margin 1e-5 >> rounding error)
    float wdx = fmaxf(fmaxf(__fsub_rn(wbnx, lx), __fsub_rn(lx, wbxx)), 0.0f);
    float wdy = fmaxf(fmaxf(__fsub_rn(wbny, ly), __fsub_rn(ly, wbxy)), 0.0f);
    float wdz = fmaxf(fmaxf(__fsub_rn(wbnz, lz), __fsub_rn(lz, wbxz)), 0.0f);
    float wlb2 = wdx * wdx + wdy * wdy + wdz * wdz;
    if (wlb2 * 0.99999f < wv) {
      float tdx = fmaxf(fmaxf(__fsub_rn(bnx, lx), __fsub_rn(lx, bxx)), 0.0f);
      float tdy = fmaxf(fmaxf(__fsub_rn(bny, ly), __fsub_rn(ly, bxy)), 0.0f);
      float tdz = fmaxf(fmaxf(__fsub_rn(bnz, lz), __fsub_rn(lz, bxz)), 0.0f);
      float tlb2 = tdx * tdx + tdy * tdy + tdz * tdz;
      bool chg = false;
      if (tlb2 * 0.99999f < my_max) {
#pragma unroll
        for (int i = 0; i < 16; ++i) {
          float dx = __fsub_rn(px[i], lx);
          float dy = __fsub_rn(py[i], ly);
          float dz = __fsub_rn(pz[i], lz);
          float d2 = __fadd_rn(__fadd_rn(__fmul_rn(dx, dx), __fmul_rn(dy, dy)), __fmul_rn(dz, dz));
          if (d2 < d[i]) { d[i] = d2; chg = true; }
        }
        if (chg) {  // rescan thread winner (lowest orig idx on ties)
          float bv = -1.0f; int bi = 0x7fffffff;
#pragma unroll
          for (int i = 0; i < 16; ++i) {
            if (d[i] > bv || (d[i] == bv && ix[i] < bi)) { bv = d[i]; bi = ix[i]; }
          }
          my_max = bv; my_arg = bi;
        }
      }
      if (__any((int)chg)) {  // wave butterfly only if something changed
        float v = my_max; int idx = my_arg;
#pragma unroll
        for (int m = 1; m < 64; m <<= 1) {
          float ov = __shfl_xor(v, m);
          int oi = __shfl_xor(idx, m);
          if (ov > v || (ov == v && oi < idx)) { v = ov; idx = oi; }
        }
        wv = v; wi = idx;
      }
    }
    if (lane == 0) { sv[wid][par] = wv; si[wid][par] = wi; }
    __syncthreads();
    float gv = sv[lane & 15][par];
    int gi = si[lane & 15][par];
#pragma unroll
    for (int m = 1; m < 16; m <<= 1) {
      float ov = __shfl_xor(gv, m);
      int oi = __shfl_xor(gi, m);
      if (ov > gv || (ov == gv && oi < gi)) { gv = ov; gi = oi; }
    }
    if (t == 0) fps_inds[b * 1024 + k] = gi;
    int w = __builtin_amdgcn_readfirstlane(gi);
    lx = base[w * 3 + 0]; ly = base[w * 3 + 1]; lz = base[w * 3 + 2];
    if (t == 0) {
      new_xyz[((size_t)b * 1024 + k) * 3 + 0] = lx;
      new_xyz[((size_t)b * 1024 + k) * 3 + 1] = ly;
      new_xyz[((size_t)b * 1024 + k) * 3 + 2] = lz;
    }
  }
}

// ---------------------------------------------------------------------------
// Ball query: one wave per center; collect first 16 in-radius indices in
// ascending index order; pad with the first. Also emits normalized grouped
// xyz (bf16, 4 elems/slot) for GEMM0's xyz channels.
// ---------------------------------------------------------------------------
__global__ __launch_bounds__(256) void ballquery_kernel(const float* __restrict__ xyz,
                                                        const float* __restrict__ new_xyz,
                                                        int* __restrict__ idxbuf,
                                                        unsigned short* __restrict__ gxyz) {
  const int wid = threadIdx.x >> 6, lane = threadIdx.x & 63;
  const int center = blockIdx.x * 4 + wid;  // 0..8191
  const int b = center >> 10;
  const float* base = xyz + (size_t)b * 49152;
  const float cx = new_xyz[(size_t)center * 3 + 0];
  const float cy = new_xyz[(size_t)center * 3 + 1];
  const float cz = new_xyz[(size_t)center * 3 + 2];
  __shared__ int slots[4][16];
  int count = 0;
  for (int c = 0; c < 256; ++c) {
    int p = c * 64 + lane;
    float dx = __fsub_rn(cx, base[p * 3 + 0]);
    float dy = __fsub_rn(cy, base[p * 3 + 1]);
    float dz = __fsub_rn(cz, base[p * 3 + 2]);
    float d2 = __fadd_rn(__fadd_rn(__fmul_rn(dx, dx), __fmul_rn(dy, dy)), __fmul_rn(dz, dz));
    bool inr = d2 < 0.09f;
    unsigned long long mask = __ballot((int)inr);
    int rank = __popcll(mask & ((1ull << lane) - 1ull));
    int pos = count + rank;
    if (inr && pos < 16) slots[wid][pos] = p;
    count += __popcll(mask);
    if (count >= 16) break;  // wave-uniform
  }
  __asm__ volatile("s_waitcnt lgkmcnt(0)" ::: "memory");
  if (lane < 16) {
    int eff = count < 16 ? count : 16;
    int p = slots[wid][lane < eff ? lane : 0];
    idxbuf[(size_t)center * 16 + lane] = p;
    float gx = (base[p * 3 + 0] - cx) * (1.0f / 0.3f);
    float gy = (base[p * 3 + 1] - cy) * (1.0f / 0.3f);
    float gz = (base[p * 3 + 2] - cz) * (1.0f / 0.3f);
    short4v o;
    o[0] = (short)f2bf(gx); o[1] = (short)f2bf(gy); o[2] = (short)f2bf(gz); o[3] = 0;
    *(short4v*)(gxyz + (size_t)center * 64 + lane * 4) = o;
  }
}

// ---------------------------------------------------------------------------
// Transpose features (B,256,16384) f32 -> featT (B*16384, 256) bf16
// ---------------------------------------------------------------------------
__global__ __launch_bounds__(256) void transpose_kernel(const float* __restrict__ feat,
                                                        unsigned short* __restrict__ featT) {
  __shared__ float tile[32][33];
  int blk = blockIdx.x;
  int pt = blk & 511;
  int ct = (blk >> 9) & 7;
  int b = blk >> 12;
  int tx = threadIdx.x & 31, ty = threadIdx.x >> 5;
  const float* src = feat + ((size_t)b * 256 + ct * 32) * 16384 + pt * 32;
#pragma unroll
  for (int q = 0; q < 4; ++q) {
    int ch = ty + q * 8;
    tile[ch][tx] = src[(size_t)ch * 16384 + tx];
  }
  __syncthreads();
  unsigned short* dst = featT + ((size_t)b * 16384 + (size_t)pt * 32) * 256 + ct * 32;
#pragma unroll
  for (int q = 0; q < 4; ++q) {
    int r = ty + q * 8;
    dst[(size_t)r * 256 + tx] = f2bf(tile[tx][r]);
  }
}

// ---------------------------------------------------------------------------
// GEMM: out(128 x ncols) = W(128 x K) * X(K x ncols), MFMA 16x16x32 bf16.
// Block: 256 threads (4 waves, 2x2), tile 128 rows x 64 cols.
// MODE 0: B gathered from featT via idxbuf + gxyz (K=288), stats, Yout bf16
// MODE 1: B from Yin with BN+ReLU applied (K=128), stats, Yout bf16
// MODE 2: B from Yin plain (K=128), stats, Yout bf16
// MODE 3: B from Yin with BN+ReLU (K=128), no stats, f32 out + bias (64 ch)
// ---------------------------------------------------------------------------
template <int MODE>
__global__ __launch_bounds__(256) void gemm_kernel(
    const unsigned short* __restrict__ W,
    const unsigned short* __restrict__ Bsrc,
    const int* __restrict__ idxbuf,
    const unsigned short* __restrict__ gxyz,
    const float* __restrict__ bnp,
    unsigned short* __restrict__ Yout,
    float* __restrict__ outf,
    const float* __restrict__ bias,
    float* __restrict__ partials) {
  constexpr bool GATHER = (MODE == 0);
  constexpr bool BNIN = (MODE == 1 || MODE == 3);
  constexpr bool STATS = (MODE <= 2);
  constexpr bool OUTF32 = (MODE == 3);
  constexpr int KCH = GATHER ? 9 : 4;
  constexpr int K = GATHER ? 288 : 128;
  __shared__ unsigned short lA[128 * 40];  // +16B padded stride vs bank conflicts
  __shared__ unsigned short lB[64 * 40];
  const int tid = threadIdx.x;
  const int wid = tid >> 6, lane = tid & 63;
  const int wr = wid >> 1, wc = wid & 1;
  const int lm = lane & 15, lg = lane >> 4;
  const int c0 = blockIdx.x * 64;
  const int colL = tid >> 2, part = tid & 3;
  const int col = c0 + colL;
  int gat_p = 0, gat_b = 0;
  if constexpr (GATHER) { gat_b = col >> 14; gat_p = idxbuf[col]; }
  f32x4 acc[4][2] = {};
  for (int q = 0; q < KCH; ++q) {
    __syncthreads();
    // stage A (weights) : 128 rows x 32 k
#pragma unroll
    for (int pass = 0; pass < 2; ++pass) {
      int u = pass * 256 + tid;
      int r = u >> 2, qq = u & 3;
      short8v w = *(const short8v*)(W + (size_t)r * K + q * 32 + qq * 8);
      *(short8v*)(&lA[r * 40 + qq * 8]) = w;
    }
    // stage B : 64 cols x 32 k
    short8v bv = short8v{0, 0, 0, 0, 0, 0, 0, 0};
    if constexpr (GATHER) {
      if (q < 8) {
        bv = *(const short8v*)(Bsrc + ((size_t)(gat_b << 14) + gat_p) * 256 + q * 32 + part * 8);
      } else if (part == 0) {
        short4v g = *(const short4v*)(gxyz + (size_t)col * 4);
        bv[0] = g[0]; bv[1] = g[1]; bv[2] = g[2];
      }
    } else {
      short8v raw = *(const short8v*)(Bsrc + (size_t)col * 128 + q * 32 + part * 8);
      if constexpr (BNIN) {
        int k0 = q * 32 + part * 8;
#pragma unroll
        for (int e = 0; e < 8; ++e) {
          float v = bf2f((unsigned short)raw[e]) * bnp[k0 + e] + bnp[128 + k0 + e];
          v = fmaxf(v, 0.0f);
          raw[e] = (short)f2bf(v);
        }
      }
      bv = raw;
    }
    *(short8v*)(&lB[colL * 40 + part * 8]) = bv;
    __syncthreads();
    // compute
    short8v b0 = *(const short8v*)(&lB[(wc * 32 + 0 + lm) * 40 + lg * 8]);
    short8v b1 = *(const short8v*)(&lB[(wc * 32 + 16 + lm) * 40 + lg * 8]);
#pragma unroll
    for (int mb = 0; mb < 4; ++mb) {
      short8v a = *(const short8v*)(&lA[(wr * 64 + mb * 16 + lm) * 40 + lg * 8]);
      acc[mb][0] = __builtin_amdgcn_mfma_f32_16x16x32_bf16(a, b0, acc[mb][0], 0, 0, 0);
      acc[mb][1] = __builtin_amdgcn_mfma_f32_16x16x32_bf16(a, b1, acc[mb][1], 0, 0, 0);
    }
  }
  // ---- epilogue ----
  if constexpr (STATS) {  // per-channel sum / sumsq partials for batch-norm
    const int slotstride = gridDim.x * 2;
    const int slot = blockIdx.x * 2 + wc;
#pragma unroll
    for (int mb = 0; mb < 4; ++mb) {
#pragma unroll
      for (int j = 0; j < 4; ++j) {
        float a0 = acc[mb][0][j], a1 = acc[mb][1][j];
        float s = a0 + a1;
        float qs = a0 * a0 + a1 * a1;
#pragma unroll
        for (int m = 1; m < 16; m <<= 1) { s += __shfl_xor(s, m); qs += __shfl_xor(qs, m); }
        if (lm == 0) {
          int ch = wr * 64 + mb * 16 + lg * 4 + j;
          partials[(size_t)(ch * 2) * slotstride + slot] = s;
          partials[(size_t)(ch * 2 + 1) * slotstride + slot] = qs;
        }
      }
    }
  }
  if constexpr (!OUTF32) {
#pragma unroll
    for (int mb = 0; mb < 4; ++mb)
#pragma unroll
      for (int nb = 0; nb < 2; ++nb) {
        int colg = c0 + wc * 32 + nb * 16 + lm;
        int ch = wr * 64 + mb * 16 + lg * 4;
#pragma unroll
        for (int j = 0; j < 4; ++j)
          Yout[(size_t)colg * 128 + ch + j] = f2bf(acc[mb][nb][j]);
      }
  } else {
    if (wr == 0) {  // only ch 0..63 are real (W padded with zero rows)
#pragma unroll
      for (int mb = 0; mb < 4; ++mb)
#pragma unroll
        for (int nb = 0; nb < 2; ++nb) {
          int colg = c0 + wc * 32 + nb * 16 + lm;
          int bb = colg >> 10, n = colg & 1023;
#pragma unroll
          for (int j = 0; j < 4; ++j) {
            int ch = mb * 16 + lg * 4 + j;
            outf[((size_t)bb * 64 + ch) * 1024 + n] = acc[mb][nb][j] + bias[ch];
          }
        }
    }
  }
}

// ---------------------------------------------------------------------------
// BN finalize: one block per channel; reduce partials -> scale/shift
// ---------------------------------------------------------------------------
__global__ __launch_bounds__(256) void bn_finalize(const float* __restrict__ part, int nslot,
                                                   float inv, const float* __restrict__ g,
                                                   const float* __restrict__ b,
                                                   float* __restrict__ bnp) {
  int ch = blockIdx.x;
  int t = threadIdx.x;
  float s1 = 0.f, s2 = 0.f;
  for (int i = t; i < nslot; i += 256) {
    s1 += part[(size_t)(ch * 2) * nslot + i];
    s2 += part[(size_t)(ch * 2 + 1) * nslot + i];
  }
  __shared__ float r1[256], r2[256];
  r1[t] = s1; r2[t] = s2;
  __syncthreads();
  for (int s = 128; s > 0; s >>= 1) {
    if (t < s) { r1[t] += r1[t + s]; r2[t] += r2[t + s]; }
    __syncthreads();
  }
  if (t == 0) {
    float m = r1[0] * inv;
    float var = r2[0] * inv - m * m;
    float sc = g[ch] * rsqrtf(var + 1e-5f);
    bnp[ch] = sc;
    bnp[128 + ch] = b[ch] - m * sc;
  }
}

// ---------------------------------------------------------------------------
// Maxpool over the 16 samples + apply BN2 + ReLU -> feat (b*n, 128) bf16
// Tracks max AND min so the BN-affine/max swap is exact for any scale sign.
// ---------------------------------------------------------------------------
__global__ __launch_bounds__(256) void maxpool_kernel(const unsigned short* __restrict__ Y2,
                                                      const float* __restrict__ bnp,
                                                      unsigned short* __restrict__ feat) {
  int gidx = blockIdx.x * 256 + threadIdx.x;  // 131072
  int ng = gidx >> 4, cg = gidx & 15;
  int ch0 = cg * 8;
  float mx[8], mn[8];
#pragma unroll
  for (int e = 0; e < 8; ++e) { mx[e] = -3.4e38f; mn[e] = 3.4e38f; }
  for (int s = 0; s < 16; ++s) {
    short8v v = *(const short8v*)(Y2 + ((size_t)ng * 16 + s) * 128 + ch0);
#pragma unroll
    for (int e = 0; e < 8; ++e) {
      float f = bf2f((unsigned short)v[e]);
      mx[e] = fmaxf(mx[e], f);
      mn[e] = fminf(mn[e], f);
    }
  }
  short8v o;
#pragma unroll
  for (int e = 0; e < 8; ++e) {
    float sc = bnp[ch0 + e], sh = bnp[128 + ch0 + e];
    float v = (sc >= 0.f ? mx[e] : mn[e]) * sc + sh;
    v = fmaxf(v, 0.0f);
    o[e] = (short)f2bf(v);
  }
  *(short8v*)(feat + (size_t)ng * 128 + ch0) = o;
}

// ---------------------------------------------------------------------------
// Weight prep: f32 -> bf16, permute W0 (features first, xyz at k=256..258),
// pad W0 K to 288, pad conv3 to 128 output rows.
// ---------------------------------------------------------------------------
__global__ __launch_bounds__(256) void prep_weights(const float* __restrict__ w0,
                                                    const float* __restrict__ w1,
                                                    const float* __restrict__ w2,
                                                    const float* __restrict__ c1,
                                                    const float* __restrict__ c2,
                                                    const float* __restrict__ c3,
                                                    unsigned short* __restrict__ W0p,
                                                    unsigned short* __restrict__ W1p,
                                                    unsigned short* __restrict__ W2p,
                                                    unsigned short* __restrict__ C1p,
                                                    unsigned short* __restrict__ C2p,
                                                    unsigned short* __restrict__ C3p) {
  int i = blockIdx.x * 256 + threadIdx.x;
  if (i < 36864) {
    int r = i / 288, c = i % 288;
    float v = 0.0f;
    if (c < 256) v = w0[r * 259 + 3 + c];
    else if (c < 259) v = w0[r * 259 + (c - 256)];
    W0p[i] = f2bf(v);
  }
  int j = i - 36864;
  if (j >= 0 && j < 16384) W1p[j] = f2bf(w1[j]);
  j -= 16384;
  if (j >= 0 && j < 16384) W2p[j] = f2bf(w2[j]);
  j -= 16384;
  if (j >= 0 && j < 16384) C1p[j] = f2bf(c1[j]);
  j -= 16384;
  if (j >= 0 && j < 16384) C2p[j] = f2bf(c2[j]);
  j -= 16384;
  if (j >= 0 && j < 16384) C3p[j] = (j < 8192) ? f2bf(c3[j]) : (unsigned short)0;
}

// ---------------------------------------------------------------------------
extern "C" void kernel_launch(void* const* d_in, const int* in_sizes, int n_in,
                              void* d_out, int out_size, void* d_ws, size_t ws_size,
                              hipStream_t stream) {
  const float* xyz = (const float*)d_in[0];
  const float* features = (const float*)d_in[1];
  const float* mlp_w0 = (const float*)d_in[2];
  const float* mlp_g0 = (const float*)d_in[3];
  const float* mlp_b0 = (const float*)d_in[4];
  const float* mlp_w1 = (const float*)d_in[5];
  const float* mlp_g1 = (const float*)d_in[6];
  const float* mlp_b1 = (const float*)d_in[7];
  const float* mlp_w2 = (const float*)d_in[8];
  const float* mlp_g2 = (const float*)d_in[9];
  const float* mlp_b2 = (const float*)d_in[10];
  const float* conv1_w = (const float*)d_in[11];
  const float* bn1_g = (const float*)d_in[13];
  const float* bn1_b = (const float*)d_in[14];
  const float* conv2_w = (const float*)d_in[15];
  const float* bn2_g = (const float*)d_in[17];
  const float* bn2_b = (const float*)d_in[18];
  const float* conv3_w = (const float*)d_in[19];
  const float* conv3_b = (const float*)d_in[20];

  char* ws = (char*)d_ws;
  int* fps_inds = (int*)(ws + 0);                    //   32768
  float* new_xyz = (float*)(ws + 32768);             //   98304
  int* idxbuf = (int*)(ws + 131072);                 //  524288
  unsigned short* gxyz = (unsigned short*)(ws + 655360);   // 1048576
  float* bnp0 = (float*)(ws + 1703936);
  float* bnp1 = (float*)(ws + 1704960);
  float* bnp2 = (float*)(ws + 1705984);
  float* bnpc1 = (float*)(ws + 1707008);
  float* bnpc2 = (float*)(ws + 1708032);
  unsigned short* W0p = (unsigned short*)(ws + 1709056);   // 73728
  unsigned short* W1p = (unsigned short*)(ws + 1782784);
  unsigned short* W2p = (unsigned short*)(ws + 1815552);
  unsigned short* C1p = (unsigned short*)(ws + 1848320);
  unsigned short* C2p = (unsigned short*)(ws + 1881088);
  unsigned short* C3p = (unsigned short*)(ws + 1913856);
  unsigned short* feat = (unsigned short*)(ws + 1946624);  // 2 MB
  unsigned short* G1 = (unsigned short*)(ws + 4043776);    // 2 MB
  unsigned short* G2 = (unsigned short*)(ws + 6140928);    // 2 MB
  float* partials = (float*)(ws + 8388608);                // 4 MB
  float* sortbuf = (float*)(ws + 12582912);                // 2 MB (8 x 65536 f32)
  unsigned short* featT = (unsigned short*)(ws + 16777216);  // 64 MB
  unsigned short* Y0 = (unsigned short*)(ws + 83886080);     // 32 MB
  unsigned short* Y1 = featT;  // featT dead after GEMM0
  unsigned short* Y2 = Y0;     // Y0 dead after GEMM1
  float* outp = (float*)d_out;

  prep_weights<<<464, 256, 0, stream>>>(mlp_w0, mlp_w1, mlp_w2, conv1_w, conv2_w, conv3_w,
                                        W0p, W1p, W2p, C1p, C2p, C3p);
  fps_kernel<<<8, 1024, 0, stream>>>(xyz, fps_inds, new_xyz, sortbuf);
  transpose_kernel<<<32768, 256, 0, stream>>>(features, featT);
  ballquery_kernel<<<2048, 256, 0, stream>>>(xyz, new_xyz, idxbuf, gxyz);

  // MLP layer 0 (K=288, gather), then BN stats
  gemm_kernel<0><<<2048, 256, 0, stream>>>(W0p, featT, idxbuf, gxyz, nullptr, Y0, nullptr,
                                           nullptr, partials);
  bn_finalize<<<128, 256, 0, stream>>>(partials, 4096, 1.0f / 131072.0f, mlp_g0, mlp_b0, bnp0);
  // MLP layer 1
  gemm_kernel<1><<<2048, 256, 0, stream>>>(W1p, Y0, nullptr, nullptr, bnp0, Y1, nullptr,
                                           nullptr, partials);
  bn_finalize<<<128, 256, 0, stream>>>(partials, 4096, 1.0f / 131072.0f, mlp_g1, mlp_b1, bnp1);
  // MLP layer 2
  gemm_kernel<1><<<2048, 256, 0, stream>>>(W2p, Y1, nullptr, nullptr, bnp1, Y2, nullptr,
                                           nullptr, partials);
  bn_finalize<<<128, 256, 0, stream>>>(partials, 4096, 1.0f / 131072.0f, mlp_g2, mlp_b2, bnp2);
  // maxpool + BN2 + ReLU
  maxpool_kernel<<<512, 256, 0, stream>>>(Y2, bnp2, feat);
  // conv1 (bias cancels under BN), stats
  gemm_kernel<2><<<128, 256, 0, stream>>>(C1p, feat, nullptr, nullptr, nullptr, G1, nullptr,
                                          nullptr, partials);
  bn_finalize<<<128, 256, 0, stream>>>(partials, 256, 1.0f / 8192.0f, bn1_g, bn1_b, bnpc1);
  // conv2 (applies BN1+ReLU on input; bias cancels under BN), stats
  gemm_kernel<1><<<128, 256, 0, stream>>>(C2p, G1, nullptr, nullptr, bnpc1, G2, nullptr,
                                          nullptr, partials);
  bn_finalize<<<128, 256, 0, stream>>>(partials, 256, 1.0f / 8192.0f, bn2_g, bn2_b, bnpc2);
  // conv3 (applies BN2+ReLU on input; +bias; f32 out)
  gemm_kernel<3><<<128, 256, 0, stream>>>(C3p, G2, nullptr, nullptr, bnpc2, nullptr, outp,
                                          conv3_b, partials);
  (void)in_sizes; (void)n_in; (void)out_size; (void)ws_size;
}